// Round 2
// baseline (389.780 us; speedup 1.0000x reference)
//
#include <hip/hip_runtime.h>

// ws layout (bytes):
//   bpack  : [64][32][64][8] ushort (bf16)  = 2 MB   @ 0
//   h_ws   : [64][1024][16] float           = 4 MB   @ 2 MB
//   cs_part: [64][16][8][128] float         = 4 MB   @ 6 MB

typedef __attribute__((ext_vector_type(8))) short short8;
typedef __attribute__((ext_vector_type(4))) float f32x4;

__device__ __forceinline__ unsigned short f2bf(float f) {
    unsigned int u = __float_as_uint(f);
    u += 0x7FFFu + ((u >> 16) & 1u);
    return (unsigned short)(u >> 16);
}

// ---------------- Kernel A: m1 = tanh(x@W1+b1), stored in B-fragment order --
// thread g -> (b, kc, slot): writes 8 bf16 = m1[b][kc*32+(slot>>4)*8+j][slot&15]
__global__ __launch_bounds__(256) void k_mlp1(const float* __restrict__ x,
                                              const float* __restrict__ W1,
                                              const float* __restrict__ b1,
                                              unsigned short* __restrict__ bpack) {
    int g = blockIdx.x * 256 + threadIdx.x;   // 131072 total
    int slot = g & 63;
    int b_kc = g >> 6;                         // b*32 + kc
    int d = slot & 15, q = slot >> 4;
    int kc = b_kc & 31, b = b_kc >> 5;
    int m0 = kc * 32 + q * 8;
    const float* xp = x + (size_t)(b * 1024 + m0) * 3;
    float w0 = 0.f, w1 = 0.f, w2 = 0.f, bb = 0.f;
    if (d < 10) { w0 = W1[d]; w1 = W1[10 + d]; w2 = W1[20 + d]; bb = b1[d]; }
    unsigned int o[8];
#pragma unroll
    for (int j = 0; j < 8; ++j) {
        float v = 0.f;
        if (d < 10) v = tanhf(xp[j*3] * w0 + xp[j*3+1] * w1 + xp[j*3+2] * w2 + bb);
        o[j] = f2bf(v);
    }
    uint4 pk;
    pk.x = o[0] | (o[1] << 16);
    pk.y = o[2] | (o[3] << 16);
    pk.z = o[4] | (o[5] << 16);
    pk.w = o[6] | (o[7] << 16);
    *(uint4*)(bpack + (size_t)g * 8) = pk;
}

// ---------------- Kernel B: h = adj @ m1 (MFMA) + fused column-sum ----------
// grid: 64 b * 16 row-tiles; block 256 thr / 4 waves; wave w owns rows n0+w*16..+15
__global__ __launch_bounds__(256) void k_agg(const float* __restrict__ adj,
                                             const unsigned short* __restrict__ bpack,
                                             float* __restrict__ h_ws,
                                             float* __restrict__ cs_part) {
    __shared__ __align__(16) unsigned short aT[64 * 128];  // 16 KB, XOR-swizzled
    __shared__ __align__(16) unsigned short bP[16384];     // 32 KB B-fragments
    __shared__ float csb[4 * 128];                         // 2 KB colsum partials

    const int t = threadIdx.x;
    const int b = blockIdx.x >> 4;
    const int tile = blockIdx.x & 15;
    const int n0 = tile * 64;
    const int l = t & 63, w = t >> 6;
    const int rgrp = t >> 5;      // 0..7: row residue class this thread stages
    const int c32 = t & 31;       // column group (4 floats)

    // stage all B-fragments for this b (32 KB), covered by first kstep barrier
    {
        const uint4* bg = (const uint4*)(bpack + (size_t)b * 16384);
        uint4* bl = (uint4*)bP;
#pragma unroll
        for (int i = 0; i < 8; ++i) bl[i * 256 + t] = bg[i * 256 + t];
    }

    f32x4 acc = {0.f, 0.f, 0.f, 0.f};

    for (int kstep = 0; kstep < 8; ++kstep) {
        float cs0 = 0.f, cs1 = 0.f, cs2 = 0.f, cs3 = 0.f;
        // ---- stage A tile 64x128 f32 -> bf16 (swizzled), accumulate colsum --
#pragma unroll
        for (int i = 0; i < 8; ++i) {
            int row = i * 8 + rgrp;
            int col = c32 * 4;
            const float4 a = *(const float4*)(adj
                + (size_t)(b * 1024 + n0 + row) * 1024 + kstep * 128 + col);
            cs0 += a.x; cs1 += a.y; cs2 += a.z; cs3 += a.w;
            unsigned int lo = f2bf(a.x) | ((unsigned)f2bf(a.y) << 16);
            unsigned int hi = f2bf(a.z) | ((unsigned)f2bf(a.w) << 16);
            unsigned bo = (unsigned)(row * 256 + col * 2);
            bo ^= (unsigned)((row & 7) << 4);
            *(uint2*)((char*)aT + bo) = make_uint2(lo, hi);
        }
        // colsum: pair-combine rgrp within wave (lanes l and l^32 share columns)
        cs0 += __shfl_xor(cs0, 32); cs1 += __shfl_xor(cs1, 32);
        cs2 += __shfl_xor(cs2, 32); cs3 += __shfl_xor(cs3, 32);
        if (l < 32)
            *(float4*)&csb[w * 128 + l * 4] = make_float4(cs0, cs1, cs2, cs3);
        __syncthreads();
        // ---- MFMA: 4 k-chunks of 32 --------------------------------------
#pragma unroll
        for (int kc = 0; kc < 4; ++kc) {
            int lrow = w * 16 + (l & 15);
            unsigned bo = (unsigned)(lrow * 256 + kc * 64 + (l >> 4) * 16);
            bo ^= (unsigned)((lrow & 7) << 4);
            short8 af = *(const short8*)((char*)aT + bo);
            short8 bf = *((const short8*)bP + (kstep * 4 + kc) * 64 + l);
            acc = __builtin_amdgcn_mfma_f32_16x16x32_bf16(af, bf, acc, 0, 0, 0);
        }
        // ---- colsum partial for this kstep (128 m-values per block) -------
        if (t < 128) {
            float s = csb[t] + csb[128 + t] + csb[256 + t] + csb[384 + t];
            cs_part[(((size_t)b * 16 + tile) * 8 + kstep) * 128 + t] = s;
        }
        __syncthreads();
    }
    // ---- write h (C/D layout: col=lane&15, row=(lane>>4)*4+reg) -----------
    {
        int col = l & 15, rb = (l >> 4) * 4;
#pragma unroll
        for (int r = 0; r < 4; ++r) {
            int n = n0 + w * 16 + rb + r;
            h_ws[((size_t)(b * 1024 + n) << 4) + col] = acc[r];
        }
    }
}

// ---------------- Kernel C: colsum reduce, m2=tanh(h@W2+b2), pool, readout --
__global__ __launch_bounds__(256) void k_read(const float* __restrict__ h_ws,
                                              const float* __restrict__ cs_part,
                                              const float* __restrict__ W2,
                                              const float* __restrict__ b2,
                                              const float* __restrict__ W3,
                                              const float* __restrict__ b3,
                                              float* __restrict__ out) {
    int b = blockIdx.x, t = threadIdx.x;
    float pool[10];
#pragma unroll
    for (int d = 0; d < 10; ++d) pool[d] = 0.f;

    for (int it = 0; it < 4; ++it) {
        int m = it * 256 + t;
        float cs = 0.f;
#pragma unroll
        for (int tile = 0; tile < 16; ++tile)
            cs += cs_part[(((size_t)b * 16 + tile) * 8 + (m >> 7)) * 128 + (m & 127)];
        const float* hp = h_ws + ((size_t)(b * 1024 + m) << 4);
        float hv[10];
#pragma unroll
        for (int d = 0; d < 10; ++d) hv[d] = hp[d];
#pragma unroll
        for (int dp = 0; dp < 10; ++dp) {
            float s = b2[dp];
#pragma unroll
            for (int d = 0; d < 10; ++d) s += hv[d] * W2[d * 10 + dp];
            pool[dp] += cs * tanhf(s);
        }
    }
    // wave reduce (64 lanes)
#pragma unroll
    for (int d = 0; d < 10; ++d) {
        float v = pool[d];
        v += __shfl_xor(v, 1);  v += __shfl_xor(v, 2);  v += __shfl_xor(v, 4);
        v += __shfl_xor(v, 8);  v += __shfl_xor(v, 16); v += __shfl_xor(v, 32);
        pool[d] = v;
    }
    __shared__ float red[4][10];
    int l = t & 63, w = t >> 6;
    if (l == 0) {
#pragma unroll
        for (int d = 0; d < 10; ++d) red[w][d] = pool[d];
    }
    __syncthreads();
    if (t < 2) {
        float s = b3[t];
#pragma unroll
        for (int dp = 0; dp < 10; ++dp) {
            float p = red[0][dp] + red[1][dp] + red[2][dp] + red[3][dp];
            s += p * W3[dp * 2 + t];
        }
        out[b * 2 + t] = s;
    }
}

extern "C" void kernel_launch(void* const* d_in, const int* in_sizes, int n_in,
                              void* d_out, int out_size, void* d_ws, size_t ws_size,
                              hipStream_t stream) {
    (void)in_sizes; (void)n_in; (void)out_size; (void)ws_size;
    const float* x   = (const float*)d_in[0];
    const float* adj = (const float*)d_in[1];
    const float* W1  = (const float*)d_in[2];
    const float* b1  = (const float*)d_in[3];
    const float* W2  = (const float*)d_in[4];
    const float* b2  = (const float*)d_in[5];
    const float* W3  = (const float*)d_in[6];
    const float* b3  = (const float*)d_in[7];
    float* out = (float*)d_out;

    char* ws = (char*)d_ws;
    unsigned short* bpack = (unsigned short*)ws;          // 2 MB
    float* h_ws    = (float*)(ws + (2u << 20));           // 4 MB
    float* cs_part = (float*)(ws + (6u << 20));           // 4 MB

    k_mlp1<<<512, 256, 0, stream>>>(x, W1, b1, bpack);
    k_agg<<<1024, 256, 0, stream>>>(adj, bpack, h_ws, cs_part);
    k_read<<<64, 256, 0, stream>>>(h_ws, cs_part, W2, b2, W3, b3, out);
}

// Round 3
// 383.334 us; speedup vs baseline: 1.0168x; 1.0168x over previous
//
#include <hip/hip_runtime.h>

// ws layout (bytes):
//   bpack  : [64][32][64][8] ushort (bf16)  = 2 MB   @ 0
//   h_ws   : [64][1024][16] float           = 4 MB   @ 2 MB
//   cs_part: [64][16][8][128] float         = 4 MB   @ 6 MB

typedef __attribute__((ext_vector_type(8))) short short8;
typedef __attribute__((ext_vector_type(4))) float f32x4;

__device__ __forceinline__ unsigned short f2bf(float f) {
    unsigned int u = __float_as_uint(f);
    u += 0x7FFFu + ((u >> 16) & 1u);
    return (unsigned short)(u >> 16);
}

// ---------------- Kernel A: m1 = tanh(x@W1+b1), stored in B-fragment order --
// thread g -> (b, kc, slot): writes 8 bf16 = m1[b][kc*32+(slot>>4)*8+j][slot&15]
__global__ __launch_bounds__(256) void k_mlp1(const float* __restrict__ x,
                                              const float* __restrict__ W1,
                                              const float* __restrict__ b1,
                                              unsigned short* __restrict__ bpack) {
    int g = blockIdx.x * 256 + threadIdx.x;   // 131072 total
    int slot = g & 63;
    int b_kc = g >> 6;                         // b*32 + kc
    int d = slot & 15, q = slot >> 4;
    int kc = b_kc & 31, b = b_kc >> 5;
    int m0 = kc * 32 + q * 8;
    const float* xp = x + (size_t)(b * 1024 + m0) * 3;
    float w0 = 0.f, w1 = 0.f, w2 = 0.f, bb = 0.f;
    if (d < 10) { w0 = W1[d]; w1 = W1[10 + d]; w2 = W1[20 + d]; bb = b1[d]; }
    unsigned int o[8];
#pragma unroll
    for (int j = 0; j < 8; ++j) {
        float v = 0.f;
        if (d < 10) v = tanhf(xp[j*3] * w0 + xp[j*3+1] * w1 + xp[j*3+2] * w2 + bb);
        o[j] = f2bf(v);
    }
    uint4 pk;
    pk.x = o[0] | (o[1] << 16);
    pk.y = o[2] | (o[3] << 16);
    pk.z = o[4] | (o[5] << 16);
    pk.w = o[6] | (o[7] << 16);
    *(uint4*)(bpack + (size_t)g * 8) = pk;
}

// ---- staging helper: f32x4[8] -> bf16 swizzled LDS tile + colsum partials --
__device__ __forceinline__ void cvt_store(const float4* a, unsigned short* aTb,
                                          float* csbb, int rgrp, int c32,
                                          int w, int l) {
    float cs0 = 0.f, cs1 = 0.f, cs2 = 0.f, cs3 = 0.f;
#pragma unroll
    for (int i = 0; i < 8; ++i) {
        int row = i * 8 + rgrp;
        cs0 += a[i].x; cs1 += a[i].y; cs2 += a[i].z; cs3 += a[i].w;
        unsigned int lo = f2bf(a[i].x) | ((unsigned)f2bf(a[i].y) << 16);
        unsigned int hi = f2bf(a[i].z) | ((unsigned)f2bf(a[i].w) << 16);
        unsigned bo = (unsigned)(row * 256 + c32 * 8);
        bo ^= (unsigned)((row & 7) << 4);
        *(uint2*)((char*)aTb + bo) = make_uint2(lo, hi);
    }
    // lanes l and l^32 share columns (c32 identical), rows differ -> pair-sum
    cs0 += __shfl_xor(cs0, 32); cs1 += __shfl_xor(cs1, 32);
    cs2 += __shfl_xor(cs2, 32); cs3 += __shfl_xor(cs3, 32);
    if (l < 32)
        *(float4*)&csbb[w * 128 + l * 4] = make_float4(cs0, cs1, cs2, cs3);
}

// ---------------- Kernel B: h = adj @ m1 (MFMA) + fused column-sum ----------
// grid: 64 b * 16 row-tiles; 256 thr / 4 waves; wave w owns rows n0+w*16..+15
// Single barrier per kstep: aT/csb double-buffered, next-kstep loads issued
// before MFMA (latency hides under MFMA + cs_part write), B-frags from L2.
__global__ __launch_bounds__(256) void k_agg(const float* __restrict__ adj,
                                             const unsigned short* __restrict__ bpack,
                                             float* __restrict__ h_ws,
                                             float* __restrict__ cs_part) {
    __shared__ __align__(16) unsigned short aT[2][64 * 128];  // 2 x 16 KB
    __shared__ float csb[2][4 * 128];                         // 2 x 2 KB

    const int t = threadIdx.x;
    const int b = blockIdx.x >> 4;
    const int tile = blockIdx.x & 15;
    const int n0 = tile * 64;
    const int l = t & 63, w = t >> 6;
    const int rgrp = t >> 5;      // 0..7: row residue class this thread stages
    const int c32 = t & 31;       // column group (4 floats)

    const float* adj_base = adj + (size_t)(b * 1024 + n0) * 1024;
    const short8* bfrag = (const short8*)(bpack + (size_t)b * 16384);

    // prologue: stage kstep 0
    {
        float4 a0[8];
#pragma unroll
        for (int i = 0; i < 8; ++i)
            a0[i] = *(const float4*)(adj_base + (size_t)(i * 8 + rgrp) * 1024 + c32 * 4);
        cvt_store(a0, aT[0], csb[0], rgrp, c32, w, l);
    }
    __syncthreads();

    f32x4 acc = {0.f, 0.f, 0.f, 0.f};
    int p = 0;
    const int lrow = w * 16 + (l & 15);
    const int lcol0 = (l >> 4) * 16;

    for (int k = 0; k < 8; ++k) {
        float4 nx[8];
        if (k < 7) {    // issue next kstep's loads; consumed only in cvt_store
#pragma unroll
            for (int i = 0; i < 8; ++i)
                nx[i] = *(const float4*)(adj_base
                    + (size_t)(i * 8 + rgrp) * 1024 + (k + 1) * 128 + c32 * 4);
        }
        // MFMA on buf p (B-fragments straight from L2-resident bpack)
#pragma unroll
        for (int kc = 0; kc < 4; ++kc) {
            unsigned bo = (unsigned)(lrow * 256 + kc * 64 + lcol0);
            bo ^= (unsigned)((lrow & 7) << 4);
            short8 af = *(const short8*)((char*)aT[p] + bo);
            short8 bf = bfrag[(k * 4 + kc) * 64 + l];
            acc = __builtin_amdgcn_mfma_f32_16x16x32_bf16(af, bf, acc, 0, 0, 0);
        }
        // colsum partial for this kstep (128 m-values per block)
        if (t < 128) {
            float s = csb[p][t] + csb[p][128 + t] + csb[p][256 + t] + csb[p][384 + t];
            cs_part[(((size_t)b * 16 + tile) * 8 + k) * 128 + t] = s;
        }
        if (k < 7) {
            cvt_store(nx, aT[p ^ 1], csb[p ^ 1], rgrp, c32, w, l);
            __syncthreads();
            p ^= 1;
        }
    }
    // ---- write h (C/D layout: col=lane&15, row=(lane>>4)*4+reg) -----------
    {
        int col = l & 15, rb = (l >> 4) * 4;
#pragma unroll
        for (int r = 0; r < 4; ++r) {
            int n = n0 + w * 16 + rb + r;
            h_ws[((size_t)(b * 1024 + n) << 4) + col] = acc[r];
        }
    }
}

// ---------------- Kernel C: colsum reduce, m2=tanh(h@W2+b2), pool, readout --
__global__ __launch_bounds__(256) void k_read(const float* __restrict__ h_ws,
                                              const float* __restrict__ cs_part,
                                              const float* __restrict__ W2,
                                              const float* __restrict__ b2,
                                              const float* __restrict__ W3,
                                              const float* __restrict__ b3,
                                              float* __restrict__ out) {
    int b = blockIdx.x, t = threadIdx.x;
    float pool[10];
#pragma unroll
    for (int d = 0; d < 10; ++d) pool[d] = 0.f;

    for (int it = 0; it < 4; ++it) {
        int m = it * 256 + t;
        float cs = 0.f;
#pragma unroll
        for (int tile = 0; tile < 16; ++tile)
            cs += cs_part[(((size_t)b * 16 + tile) * 8 + (m >> 7)) * 128 + (m & 127)];
        const float* hp = h_ws + ((size_t)(b * 1024 + m) << 4);
        float hv[10];
#pragma unroll
        for (int d = 0; d < 10; ++d) hv[d] = hp[d];
#pragma unroll
        for (int dp = 0; dp < 10; ++dp) {
            float s = b2[dp];
#pragma unroll
            for (int d = 0; d < 10; ++d) s += hv[d] * W2[d * 10 + dp];
            pool[dp] += cs * tanhf(s);
        }
    }
    // wave reduce (64 lanes)
#pragma unroll
    for (int d = 0; d < 10; ++d) {
        float v = pool[d];
        v += __shfl_xor(v, 1);  v += __shfl_xor(v, 2);  v += __shfl_xor(v, 4);
        v += __shfl_xor(v, 8);  v += __shfl_xor(v, 16); v += __shfl_xor(v, 32);
        pool[d] = v;
    }
    __shared__ float red[4][10];
    int l = t & 63, w = t >> 6;
    if (l == 0) {
#pragma unroll
        for (int d = 0; d < 10; ++d) red[w][d] = pool[d];
    }
    __syncthreads();
    if (t < 2) {
        float s = b3[t];
#pragma unroll
        for (int dp = 0; dp < 10; ++dp) {
            float p = red[0][dp] + red[1][dp] + red[2][dp] + red[3][dp];
            s += p * W3[dp * 2 + t];
        }
        out[b * 2 + t] = s;
    }
}

extern "C" void kernel_launch(void* const* d_in, const int* in_sizes, int n_in,
                              void* d_out, int out_size, void* d_ws, size_t ws_size,
                              hipStream_t stream) {
    (void)in_sizes; (void)n_in; (void)out_size; (void)ws_size;
    const float* x   = (const float*)d_in[0];
    const float* adj = (const float*)d_in[1];
    const float* W1  = (const float*)d_in[2];
    const float* b1  = (const float*)d_in[3];
    const float* W2  = (const float*)d_in[4];
    const float* b2  = (const float*)d_in[5];
    const float* W3  = (const float*)d_in[6];
    const float* b3  = (const float*)d_in[7];
    float* out = (float*)d_out;

    char* ws = (char*)d_ws;
    unsigned short* bpack = (unsigned short*)ws;          // 2 MB
    float* h_ws    = (float*)(ws + (2u << 20));           // 4 MB
    float* cs_part = (float*)(ws + (6u << 20));           // 4 MB

    k_mlp1<<<512, 256, 0, stream>>>(x, W1, b1, bpack);
    k_agg<<<1024, 256, 0, stream>>>(adj, bpack, h_ws, cs_part);
    k_read<<<64, 256, 0, stream>>>(h_ws, cs_part, W2, b2, W3, b3, out);
}

// Round 4
// 373.036 us; speedup vs baseline: 1.0449x; 1.0276x over previous
//
#include <hip/hip_runtime.h>

// ws layout (bytes):
//   bpack  : [64][32][64][8] ushort (bf16)  = 2 MB   @ 0
//   m2c    : [64][1024][16] float           = 4 MB   @ 2 MB  (only [0..9] valid)
//   cs_part: [64][16][8][128] float         = 4 MB   @ 6 MB

typedef __attribute__((ext_vector_type(8))) short short8;
typedef __attribute__((ext_vector_type(4))) float f32x4;

__device__ __forceinline__ unsigned short f2bf(float f) {
    unsigned int u = __float_as_uint(f);
    u += 0x7FFFu + ((u >> 16) & 1u);
    return (unsigned short)(u >> 16);
}

// ---------------- Kernel A: m1 = tanh(x@W1+b1), stored in B-fragment order --
__global__ __launch_bounds__(256) void k_mlp1(const float* __restrict__ x,
                                              const float* __restrict__ W1,
                                              const float* __restrict__ b1,
                                              unsigned short* __restrict__ bpack) {
    int g = blockIdx.x * 256 + threadIdx.x;   // 131072 total
    int slot = g & 63;
    int b_kc = g >> 6;
    int d = slot & 15, q = slot >> 4;
    int kc = b_kc & 31, b = b_kc >> 5;
    int m0 = kc * 32 + q * 8;
    const float* xp = x + (size_t)(b * 1024 + m0) * 3;
    float w0 = 0.f, w1 = 0.f, w2 = 0.f, bb = 0.f;
    if (d < 10) { w0 = W1[d]; w1 = W1[10 + d]; w2 = W1[20 + d]; bb = b1[d]; }
    unsigned int o[8];
#pragma unroll
    for (int j = 0; j < 8; ++j) {
        float v = 0.f;
        if (d < 10) v = tanhf(xp[j*3] * w0 + xp[j*3+1] * w1 + xp[j*3+2] * w2 + bb);
        o[j] = f2bf(v);
    }
    uint4 pk;
    pk.x = o[0] | (o[1] << 16);
    pk.y = o[2] | (o[3] << 16);
    pk.z = o[4] | (o[5] << 16);
    pk.w = o[6] | (o[7] << 16);
    *(uint4*)(bpack + (size_t)g * 8) = pk;
}

// ---- staging helper: f32x4[8] -> bf16 swizzled LDS tile + colsum partials --
__device__ __forceinline__ void cvt_store(const float4* a, unsigned short* aTb,
                                          float* csbb, int rgrp, int c32,
                                          int w, int l) {
    float cs0 = 0.f, cs1 = 0.f, cs2 = 0.f, cs3 = 0.f;
#pragma unroll
    for (int i = 0; i < 8; ++i) {
        int row = i * 8 + rgrp;
        cs0 += a[i].x; cs1 += a[i].y; cs2 += a[i].z; cs3 += a[i].w;
        unsigned int lo = f2bf(a[i].x) | ((unsigned)f2bf(a[i].y) << 16);
        unsigned int hi = f2bf(a[i].z) | ((unsigned)f2bf(a[i].w) << 16);
        unsigned bo = (unsigned)(row * 256 + c32 * 8);
        bo ^= (unsigned)((row & 7) << 4);
        *(uint2*)((char*)aTb + bo) = make_uint2(lo, hi);
    }
    cs0 += __shfl_xor(cs0, 32); cs1 += __shfl_xor(cs1, 32);
    cs2 += __shfl_xor(cs2, 32); cs3 += __shfl_xor(cs3, 32);
    if (l < 32)
        *(float4*)&csbb[w * 128 + l * 4] = make_float4(cs0, cs1, cs2, cs3);
}

// ---------------- Kernel B: h = adj @ m1 (MFMA) + colsum + fused m2 ---------
// Depth-2 adj prefetch (reg), depth-1 B-frag prefetch (reg), 1 barrier/kstep.
__global__ __launch_bounds__(256) void k_agg(const float* __restrict__ adj,
                                             const unsigned short* __restrict__ bpack,
                                             float* __restrict__ m2c,
                                             float* __restrict__ cs_part,
                                             const float* __restrict__ W2,
                                             const float* __restrict__ b2) {
    __shared__ __align__(16) unsigned short aT[2][64 * 128];  // 2 x 16 KB
    __shared__ float csb[2][4 * 128];                         // 2 x 2 KB

    const int t = threadIdx.x;
    const int b = blockIdx.x >> 4;
    const int tile = blockIdx.x & 15;
    const int n0 = tile * 64;
    const int l = t & 63, w = t >> 6;
    const int rgrp = t >> 5;
    const int c32 = t & 31;

    const float* adj_base = adj + (size_t)(b * 1024 + n0) * 1024;
    const short8* bfrag = (const short8*)(bpack + (size_t)b * 16384);

    float4 nxA[8], nxB[8];
    short8 bfb[4];

    // prologue: issue adj(0), adj(1), bf(0); stage kstep 0
#pragma unroll
    for (int i = 0; i < 8; ++i)
        nxA[i] = *(const float4*)(adj_base + (size_t)(i * 8 + rgrp) * 1024 + c32 * 4);
#pragma unroll
    for (int i = 0; i < 8; ++i)
        nxB[i] = *(const float4*)(adj_base + (size_t)(i * 8 + rgrp) * 1024 + 128 + c32 * 4);
#pragma unroll
    for (int kc = 0; kc < 4; ++kc) bfb[kc] = bfrag[kc * 64 + l];
    cvt_store(nxA, aT[0], csb[0], rgrp, c32, w, l);
    __syncthreads();

    f32x4 acc = {0.f, 0.f, 0.f, 0.f};
    const int lrow = w * 16 + (l & 15);
    const int lcol0 = (l >> 4) * 16;

#define K_ITER(K, NXLOAD, NXSTORE)                                             \
    {                                                                          \
        if ((K) < 6) {                                                         \
            _Pragma("unroll")                                                  \
            for (int i = 0; i < 8; ++i)                                        \
                NXLOAD[i] = *(const float4*)(adj_base                          \
                    + (size_t)(i * 8 + rgrp) * 1024 + ((K) + 2) * 128 + c32 * 4); \
        }                                                                      \
        _Pragma("unroll")                                                      \
        for (int kc = 0; kc < 4; ++kc) {                                       \
            unsigned bo = (unsigned)(lrow * 256 + kc * 64 + lcol0);            \
            bo ^= (unsigned)((lrow & 7) << 4);                                 \
            short8 af = *(const short8*)((char*)aT[(K) & 1] + bo);             \
            acc = __builtin_amdgcn_mfma_f32_16x16x32_bf16(af, bfb[kc], acc, 0, 0, 0); \
        }                                                                      \
        if ((K) < 7) {                                                         \
            _Pragma("unroll")                                                  \
            for (int kc = 0; kc < 4; ++kc)                                     \
                bfb[kc] = bfrag[(((K) + 1) * 4 + kc) * 64 + l];                \
        }                                                                      \
        if (t < 128) {                                                         \
            float s = csb[(K) & 1][t] + csb[(K) & 1][128 + t]                  \
                    + csb[(K) & 1][256 + t] + csb[(K) & 1][384 + t];           \
            cs_part[(((size_t)b * 16 + tile) * 8 + (K)) * 128 + t] = s;        \
        }                                                                      \
        if ((K) < 7) {                                                         \
            cvt_store(NXSTORE, aT[((K) + 1) & 1], csb[((K) + 1) & 1],          \
                      rgrp, c32, w, l);                                        \
            __syncthreads();                                                   \
        }                                                                      \
    }

    K_ITER(0, nxA, nxB)
    K_ITER(1, nxB, nxA)
    K_ITER(2, nxA, nxB)
    K_ITER(3, nxB, nxA)
    K_ITER(4, nxA, nxB)
    K_ITER(5, nxB, nxA)
    K_ITER(6, nxA, nxB)
    K_ITER(7, nxB, nxA)
#undef K_ITER

    // ---- epilogue: h -> LDS, m2 = tanh(h@W2+b2) -> m2c (padded 16) --------
    float* hbuf = (float*)aT;   // 4 KB; aT no longer read by anyone
    {
        int col = l & 15, rb = (l >> 4) * 4;
#pragma unroll
        for (int r = 0; r < 4; ++r)
            hbuf[(w * 16 + rb + r) * 16 + col] = acc[r];
    }
    __syncthreads();
#pragma unroll
    for (int j = 0; j < 4; ++j) {
        int slot = t + j * 256;
        int node = slot >> 4, dp = slot & 15;
        if (dp < 10) {
            float s = b2[dp];
#pragma unroll
            for (int d = 0; d < 10; ++d) s += hbuf[node * 16 + d] * W2[d * 10 + dp];
            m2c[((size_t)(b * 1024 + n0 + node) << 4) + dp] = tanhf(s);
        }
    }
}

// ---------------- Kernel C: colsum reduce, pool = colsum . m2, readout ------
__global__ __launch_bounds__(256) void k_read(const float* __restrict__ m2c,
                                              const float* __restrict__ cs_part,
                                              const float* __restrict__ W3,
                                              const float* __restrict__ b3,
                                              float* __restrict__ out) {
    int b = blockIdx.x, t = threadIdx.x;
    float pool[10];
#pragma unroll
    for (int d = 0; d < 10; ++d) pool[d] = 0.f;

    for (int it = 0; it < 4; ++it) {
        int m = it * 256 + t;
        float cs = 0.f;
#pragma unroll
        for (int tile = 0; tile < 16; ++tile)
            cs += cs_part[(((size_t)b * 16 + tile) * 8 + (m >> 7)) * 128 + (m & 127)];
        const float* mp = m2c + ((size_t)(b * 1024 + m) << 4);
        float4 v0 = *(const float4*)mp;
        float4 v1 = *(const float4*)(mp + 4);
        float2 v2 = *(const float2*)(mp + 8);
        pool[0] += cs * v0.x; pool[1] += cs * v0.y;
        pool[2] += cs * v0.z; pool[3] += cs * v0.w;
        pool[4] += cs * v1.x; pool[5] += cs * v1.y;
        pool[6] += cs * v1.z; pool[7] += cs * v1.w;
        pool[8] += cs * v2.x; pool[9] += cs * v2.y;
    }
#pragma unroll
    for (int d = 0; d < 10; ++d) {
        float v = pool[d];
        v += __shfl_xor(v, 1);  v += __shfl_xor(v, 2);  v += __shfl_xor(v, 4);
        v += __shfl_xor(v, 8);  v += __shfl_xor(v, 16); v += __shfl_xor(v, 32);
        pool[d] = v;
    }
    __shared__ float red[4][10];
    int l = t & 63, w = t >> 6;
    if (l == 0) {
#pragma unroll
        for (int d = 0; d < 10; ++d) red[w][d] = pool[d];
    }
    __syncthreads();
    if (t < 2) {
        float s = b3[t];
#pragma unroll
        for (int dp = 0; dp < 10; ++dp) {
            float p = red[0][dp] + red[1][dp] + red[2][dp] + red[3][dp];
            s += p * W3[dp * 2 + t];
        }
        out[b * 2 + t] = s;
    }
}

extern "C" void kernel_launch(void* const* d_in, const int* in_sizes, int n_in,
                              void* d_out, int out_size, void* d_ws, size_t ws_size,
                              hipStream_t stream) {
    (void)in_sizes; (void)n_in; (void)out_size; (void)ws_size;
    const float* x   = (const float*)d_in[0];
    const float* adj = (const float*)d_in[1];
    const float* W1  = (const float*)d_in[2];
    const float* b1  = (const float*)d_in[3];
    const float* W2  = (const float*)d_in[4];
    const float* b2  = (const float*)d_in[5];
    const float* W3  = (const float*)d_in[6];
    const float* b3  = (const float*)d_in[7];
    float* out = (float*)d_out;

    char* ws = (char*)d_ws;
    unsigned short* bpack = (unsigned short*)ws;          // 2 MB
    float* m2c     = (float*)(ws + (2u << 20));           // 4 MB
    float* cs_part = (float*)(ws + (6u << 20));           // 4 MB

    k_mlp1<<<512, 256, 0, stream>>>(x, W1, b1, bpack);
    k_agg<<<1024, 256, 0, stream>>>(adj, bpack, m2c, cs_part, W2, b2);
    k_read<<<64, 256, 0, stream>>>(m2c, cs_part, W3, b3, out);
}